// Round 20
// baseline (98.452 us; speedup 1.0000x reference)
//
#include <hip/hip_runtime.h>

#define Bv 2
#define Nv 5000
#define Cv 768
#define Hv 12
#define Dv 64
#define Ev 160000
#define ETOT (Ev + Nv)   // 165000 (edges + self loops)
#define HD 768
#define NEG 0.2f
#define Mv (Bv * Nv)     // 10000
#define MPAD 10240       // 80 * 128
#define DEGMAX 128       // max in-degree incl. self-loop; Poisson(33) tail -> safe
#define DEGPAD 136       // staging pad so 4-deep prefetch can overread (max idx 131)
#define DEGW 132         // s_w edge stride: 4*33 keeps 16B align, spreads banks

typedef __bf16 bf16x8 __attribute__((ext_vector_type(8)));
typedef float f32x4 __attribute__((ext_vector_type(4)));

// direct-to-LDS 16B async copy
#define GLD16(gsrc, ldst)                                                      \
  __builtin_amdgcn_global_load_lds(                                            \
      (const __attribute__((address_space(1))) unsigned int*)(gsrc),           \
      (__attribute__((address_space(3))) unsigned int*)(ldst), 16, 0, 0)

// f32 -> bf16 round-to-nearest-even
__device__ __forceinline__ unsigned short f2b(float f) {
  unsigned u = __float_as_uint(f);
  return (unsigned short)((u + 0x7FFFu + ((u >> 16) & 1u)) >> 16);
}

// ---- pre: cvt_wt blocks + one cnt-zero block (replaces hipMemsetAsync) ----
#define NB_CVTW 576    // (768/32)*(768/32)
__global__ __launch_bounds__(256) void k_pre(const float* __restrict__ W,
                                             unsigned short* __restrict__ Wt,
                                             int* __restrict__ cnt) {
  const int blk = blockIdx.x;
  const int t = threadIdx.x;
  if (blk < NB_CVTW) {
    __shared__ float s[32][33];
    const int n0 = (blk % 24) * 32, k0 = (blk / 24) * 32;
    const int tx = t & 31, ty = t >> 5;  // 32 x 8
#pragma unroll
    for (int i = 0; i < 4; ++i)
      s[ty + i * 8][tx] = W[(size_t)(k0 + ty + i * 8) * HD + n0 + tx];
    __syncthreads();
#pragma unroll
    for (int i = 0; i < 4; ++i)
      Wt[(size_t)(n0 + ty + i * 8) * Cv + k0 + tx] = f2b(s[tx][ty + i * 8]);
  } else {
    for (int i = t; i < Nv; i += 256) cnt[i] = 0;
  }
}

// ------ GEMM (dbuf, fused x-cvt) + attn-dot epilogue + CSR side-blocks -----
// Blocks 0..479: 128x128 tile, 4 waves, double-buffered LDS (2 blocks/CU);
// stage(k+1) before compute(k), one barrier/K-step. A: f32 load + cvt +
// swizzled ds_write; B: global_load_lds from wt. Blocks 480+: CSR build.
#define NB_GEMM 480
#define NB_SCAT ((ETOT + 255) / 256)   // 645
#define STAGEG(bi, kk)                                                         \
  {                                                                            \
    _Pragma("unroll")                                                          \
    for (int i = 0; i < 4; ++i) {                                              \
      const int r = i * 32 + rs;                                               \
      GLD16(Bt + (size_t)(bn + r) * Cv + (kk) + sl * 8, &Bs[bi][t * 8 + i * 2048]); \
    }                                                                          \
    float4 av[4][2];                                                           \
    _Pragma("unroll")                                                          \
    for (int i = 0; i < 4; ++i) {                                              \
      const int grow = bm + i * 32 + rs;                                       \
      if (grow < Mv) {                                                         \
        const float* ap = Ax + (size_t)grow * Cv + (kk) + ssl * 8;             \
        av[i][0] = *(const float4*)ap;                                         \
        av[i][1] = *(const float4*)(ap + 4);                                   \
      } else {                                                                 \
        av[i][0] = make_float4(0.f, 0.f, 0.f, 0.f);                            \
        av[i][1] = av[i][0];                                                   \
      }                                                                        \
    }                                                                          \
    _Pragma("unroll")                                                          \
    for (int i = 0; i < 4; ++i) {                                              \
      const int r = i * 32 + rs;                                               \
      unsigned short o[8];                                                     \
      o[0] = f2b(av[i][0].x); o[1] = f2b(av[i][0].y);                          \
      o[2] = f2b(av[i][0].z); o[3] = f2b(av[i][0].w);                          \
      o[4] = f2b(av[i][1].x); o[5] = f2b(av[i][1].y);                          \
      o[6] = f2b(av[i][1].z); o[7] = f2b(av[i][1].w);                          \
      const int ds = ssl ^ (r & 7);                                            \
      *(uint4*)&As[bi][r * 64 + ds * 8] = *(const uint4*)o;                    \
    }                                                                          \
  }

__global__ __launch_bounds__(256) void k_gemm_sc(const float* __restrict__ Ax,
                                                 const unsigned short* __restrict__ Bt,
                                                 unsigned short* __restrict__ C,
                                                 const float* __restrict__ att_src,
                                                 const float* __restrict__ att_dst,
                                                 float* __restrict__ asrc,
                                                 float* __restrict__ adst,
                                                 const int* __restrict__ ei,
                                                 int* __restrict__ cnt,
                                                 int* __restrict__ csrp) {
  if (blockIdx.x >= NB_GEMM) {
    const int e = (blockIdx.x - NB_GEMM) * 256 + threadIdx.x;
    if (e < ETOT) {
      int dst = (e < Ev) ? ei[Ev + e] : (e - Ev);
      int src = (e < Ev) ? ei[e] : (e - Ev);
      int pos = atomicAdd(&cnt[dst], 1);
      csrp[dst * DEGMAX + pos] = src;
    }
    return;
  }
  __shared__ unsigned short As[2][128 * 64];
  __shared__ unsigned short Bs[2][128 * 64];
  const int l0 = blockIdx.x;
  const int xcd = l0 & 7, j = l0 >> 3;        // j < 60
  const int bm = (xcd + 8 * (j / 6)) * 128;   // M-block pinned to xcd (0..79)
  const int bn = (j % 6) * 128;
  const int t = threadIdx.x;
  const int w = t >> 6, l = t & 63;
  const int wr = w >> 1, wc = w & 1;          // 2 x 2 wave grid
  const int g = l >> 4, li = l & 15;
  f32x4 acc[4][4] = {};

  const int rs = t >> 3;              // staging row within 32-row issue (0..31)
  const int ssl = t & 7;              // logical k-slot (A reg-staging)
  const int sl = ssl ^ (rs & 7);      // pre-swizzled slot for B's linear GLD

  STAGEG(0, 0);
  __syncthreads();
  int cur = 0;
#pragma unroll 1
  for (int step = 0; step < Cv / 64; ++step) {
    if (step + 1 < Cv / 64) STAGEG(cur ^ 1, (step + 1) * 64);
#pragma unroll
    for (int ks = 0; ks < 2; ++ks) {
      bf16x8 a[4], b[4];
#pragma unroll
      for (int mi = 0; mi < 4; ++mi) {
        const int row = wr * 64 + mi * 16 + li;
        const int slot = (ks * 4 + g) ^ (row & 7);
        a[mi] = *(const bf16x8*)&As[cur][row * 64 + slot * 8];
      }
#pragma unroll
      for (int nj = 0; nj < 4; ++nj) {
        const int row = wc * 64 + nj * 16 + li;
        const int slot = (ks * 4 + g) ^ (row & 7);
        b[nj] = *(const bf16x8*)&Bs[cur][row * 64 + slot * 8];
      }
#pragma unroll
      for (int mi = 0; mi < 4; ++mi)
#pragma unroll
        for (int nj = 0; nj < 4; ++nj)
          acc[mi][nj] = __builtin_amdgcn_mfma_f32_16x16x32_bf16(a[mi], b[nj], acc[mi][nj], 0, 0, 0);
    }
    __syncthreads();  // drains ds_write+GLD of next buf; protects cur for reuse
    cur ^= 1;
  }
  // C/D layout: col = lane&15, row = (lane>>4)*4 + reg (m89-verified)
#pragma unroll
  for (int mi = 0; mi < 4; ++mi) {
#pragma unroll
    for (int nj = 0; nj < 4; ++nj) {
      const int col = bn + wc * 64 + nj * 16 + li;
#pragma unroll
      for (int r4 = 0; r4 < 4; ++r4) {
        const int row = bm + wr * 64 + mi * 16 + g * 4 + r4;
        C[(size_t)row * HD + col] = f2b(acc[mi][nj][r4]);
      }
    }
  }
  // fused attention-dot epilogue: head covered by this wave's 64 cols
  {
    const int head = (bn >> 6) + wc;  // 2*(j%6) + wc
    float aS[4], aD[4];
#pragma unroll
    for (int nj = 0; nj < 4; ++nj) {
      aS[nj] = att_src[head * Dv + nj * 16 + li];
      aD[nj] = att_dst[head * Dv + nj * 16 + li];
    }
#pragma unroll
    for (int mi = 0; mi < 4; ++mi) {
#pragma unroll
      for (int r4 = 0; r4 < 4; ++r4) {
        float vs = 0.f, vd = 0.f;
#pragma unroll
        for (int nj = 0; nj < 4; ++nj) {
          const float hv = acc[mi][nj][r4];
          vs = fmaf(hv, aS[nj], vs);
          vd = fmaf(hv, aD[nj], vd);
        }
        vs += __shfl_xor(vs, 1); vd += __shfl_xor(vd, 1);
        vs += __shfl_xor(vs, 2); vd += __shfl_xor(vd, 2);
        vs += __shfl_xor(vs, 4); vd += __shfl_xor(vd, 4);
        vs += __shfl_xor(vs, 8); vd += __shfl_xor(vd, 8);
        const int row = bm + wr * 64 + mi * 16 + g * 4 + r4;
        if (li == 0 && row < Mv) {
          asrc[(size_t)row * Hv + head] = vs;
          adst[(size_t)row * Hv + head] = vd;
        }
      }
    }
  }
}

// ------- fused softmax + aggregation: block per n, BOTH batches ------------
// The edge list is batch-independent: one s_src staging serves both units,
// and the two 96-lane units have IDENTICAL deg -> zero intra-block imbalance
// (vs pairing two nodes: E[max(d0,d1)] ~ 9% over mean). 192 threads =
// 2 batches x 96 lanes; grid Nv = 5000.
#define EDGE_FMA(c, wv)                                              \
  {                                                                  \
    acc[0] = fmaf(wv, __uint_as_float((c).x << 16), acc[0]);         \
    acc[1] = fmaf(wv, __uint_as_float((c).x & 0xFFFF0000u), acc[1]); \
    acc[2] = fmaf(wv, __uint_as_float((c).y << 16), acc[2]);         \
    acc[3] = fmaf(wv, __uint_as_float((c).y & 0xFFFF0000u), acc[3]); \
    acc[4] = fmaf(wv, __uint_as_float((c).z << 16), acc[4]);         \
    acc[5] = fmaf(wv, __uint_as_float((c).z & 0xFFFF0000u), acc[5]); \
    acc[6] = fmaf(wv, __uint_as_float((c).w << 16), acc[6]);         \
    acc[7] = fmaf(wv, __uint_as_float((c).w & 0xFFFF0000u), acc[7]); \
  }

__global__ __launch_bounds__(192) void k_agg(const unsigned short* __restrict__ h2,
                                             const int* __restrict__ cnt,
                                             const int* __restrict__ csrp,
                                             const float* __restrict__ asrc,
                                             const float* __restrict__ adst,
                                             const float* __restrict__ bias,
                                             float* __restrict__ out) {
  const int n = blockIdx.x;
  const int t = threadIdx.x;
  __shared__ int s_src[DEGPAD];
  __shared__ float s_w[2][Hv][DEGW];
  __shared__ float s_inv[2][16];
  const int deg = cnt[n];                 // <= DEGMAX, shared by both batches
  const int degp = (deg + 7) & ~7;
  for (int i = t; i < DEGPAD; i += 192) {
    int sv = 0;
    if (i < deg) sv = csrp[n * DEGMAX + i];
    s_src[i] = sv;  // pad with row 0 (safe to load, weight = 0)
  }
  __syncthreads();
  // Phase A: (batch bb, head-quad q, slot): one f32x4 asrc load serves 4 heads
  {
    const int bb = t / 96, rq = t % 96;
    const int q = rq >> 5, slot = rq & 31;   // q = head quad (0..2)
    const f32x4 adv4 = *(const f32x4*)&adst[((size_t)bb * Nv + n) * Hv + q * 4];
    f32x4 ps = {0.f, 0.f, 0.f, 0.f};
    for (int i = slot; i < deg; i += 32) {
      const int src = s_src[i];
      const f32x4 as4 = *(const f32x4*)&asrc[((size_t)bb * Nv + src) * Hv + q * 4];
#pragma unroll
      for (int jq = 0; jq < 4; ++jq) {
        float v = as4[jq] + adv4[jq];
        v = fmaxf(v, NEG * v);      // leaky_relu
        float ex = __expf(v);
        s_w[bb][q * 4 + jq][i] = ex;
        ps[jq] += ex;
      }
    }
    for (int i = deg + slot; i < degp; i += 32) {
#pragma unroll
      for (int jq = 0; jq < 4; ++jq) s_w[bb][q * 4 + jq][i] = 0.f;
    }
#pragma unroll
    for (int jq = 0; jq < 4; ++jq) {
      ps[jq] += __shfl_xor(ps[jq], 1);
      ps[jq] += __shfl_xor(ps[jq], 2);
      ps[jq] += __shfl_xor(ps[jq], 4);
      ps[jq] += __shfl_xor(ps[jq], 8);
      ps[jq] += __shfl_xor(ps[jq], 16);
    }
    if (slot == 0) {
      f32x4 inv;
#pragma unroll
      for (int jq = 0; jq < 4; ++jq) inv[jq] = 1.0f / (ps[jq] + 1e-16f);
      *(f32x4*)&s_inv[bb][q * 4] = inv;
    }
  }
  __syncthreads();
  // Phase B: batch bb, lane tl owns dims [8tl, 8tl+8); no guards (0-padded w)
  const int bb = t >= 96;
  const int tl = t - bb * 96;
  const int hl = tl >> 3;  // head
  float acc[8] = {};
  const unsigned short* hrow = h2 + (size_t)bb * Nv * HD + tl * 8;
  uint4 cA[4], cB[4];
#pragma unroll
  for (int k = 0; k < 4; ++k)
    cA[k] = *(const uint4*)(hrow + (size_t)s_src[k] * HD);
  for (int base = 0; base < degp; base += 8) {
#pragma unroll
    for (int k = 0; k < 4; ++k)
      cB[k] = *(const uint4*)(hrow + (size_t)s_src[base + 4 + k] * HD);
    {
      const f32x4 w4 = *(const f32x4*)&s_w[bb][hl][base];
      EDGE_FMA(cA[0], w4[0]); EDGE_FMA(cA[1], w4[1]);
      EDGE_FMA(cA[2], w4[2]); EDGE_FMA(cA[3], w4[3]);
    }
#pragma unroll
    for (int k = 0; k < 4; ++k)
      cA[k] = *(const uint4*)(hrow + (size_t)s_src[base + 8 + k] * HD);  // max 131 < DEGPAD
    {
      const f32x4 w4 = *(const f32x4*)&s_w[bb][hl][base + 4];
      EDGE_FMA(cB[0], w4[0]); EDGE_FMA(cB[1], w4[1]);
      EDGE_FMA(cB[2], w4[2]); EDGE_FMA(cB[3], w4[3]);
    }
  }
  const float invh = s_inv[bb][hl];
  const int od = tl * 8;
  float4 o0, o1;
  o0.x = fmaf(acc[0], invh, bias[od + 0]);
  o0.y = fmaf(acc[1], invh, bias[od + 1]);
  o0.z = fmaf(acc[2], invh, bias[od + 2]);
  o0.w = fmaf(acc[3], invh, bias[od + 3]);
  o1.x = fmaf(acc[4], invh, bias[od + 4]);
  o1.y = fmaf(acc[5], invh, bias[od + 5]);
  o1.z = fmaf(acc[6], invh, bias[od + 6]);
  o1.w = fmaf(acc[7], invh, bias[od + 7]);
  float* op = out + ((size_t)bb * Nv + n) * HD + od;
  *(float4*)op = o0;
  *(float4*)(op + 4) = o1;
}

extern "C" void kernel_launch(void* const* d_in, const int* in_sizes, int n_in,
                              void* d_out, int out_size, void* d_ws, size_t ws_size,
                              hipStream_t stream) {
  const float* x = (const float*)d_in[0];
  const float* W = (const float*)d_in[1];
  const float* att_src = (const float*)d_in[2];
  const float* att_dst = (const float*)d_in[3];
  const float* bias = (const float*)d_in[4];
  const int* ei = (const int*)d_in[5];
  float* out = (float*)d_out;

  // workspace layout
  unsigned short* h2 = (unsigned short*)d_ws;            // MPAD*768 bf16
  unsigned short* wt = h2 + (size_t)MPAD * HD;           // 768*768 bf16
  float* asrc = (float*)(wt + (size_t)HD * Cv);          // 120,000 f32
  float* adst = asrc + (size_t)Bv * Nv * Hv;             // 120,000 f32
  int* cnt = (int*)(adst + (size_t)Bv * Nv * Hv);        // Nv (count AND cursor)
  int* csrp = cnt + Nv;                                  // Nv*DEGMAX padded CSR

  k_pre<<<NB_CVTW + 1, 256, 0, stream>>>(W, wt, cnt);
  k_gemm_sc<<<NB_GEMM + NB_SCAT, 256, 0, stream>>>(x, wt, h2, att_src, att_dst,
                                                   asrc, adst, ei, cnt, csrp);
  k_agg<<<Nv, 192, 0, stream>>>(h2, cnt, csrp, asrc, adst, bias, out);
}

// Round 21
// 83.620 us; speedup vs baseline: 1.1774x; 1.1774x over previous
//
#include <hip/hip_runtime.h>

#define Bv 2
#define Nv 5000
#define Cv 768
#define Hv 12
#define Dv 64
#define Ev 160000
#define ETOT (Ev + Nv)   // 165000 (edges + self loops)
#define HD 768
#define NEG 0.2f
#define Mv (Bv * Nv)     // 10000
#define MPAD 10240       // 80 * 128
#define DEGMAX 128       // max in-degree incl. self-loop; Poisson(33) tail -> safe
#define DEGPAD 136       // staging pad so 4-deep prefetch can overread (max idx 131)
#define DEGW 132         // s_w edge stride: 4*33 keeps 16B align, spreads banks

typedef __bf16 bf16x8 __attribute__((ext_vector_type(8)));
typedef float f32x4 __attribute__((ext_vector_type(4)));

// direct-to-LDS 16B async copy
#define GLD16(gsrc, ldst)                                                      \
  __builtin_amdgcn_global_load_lds(                                            \
      (const __attribute__((address_space(1))) unsigned int*)(gsrc),           \
      (__attribute__((address_space(3))) unsigned int*)(ldst), 16, 0, 0)

// f32 -> bf16 round-to-nearest-even
__device__ __forceinline__ unsigned short f2b(float f) {
  unsigned u = __float_as_uint(f);
  return (unsigned short)((u + 0x7FFFu + ((u >> 16) & 1u)) >> 16);
}

// ---- pre: cvt_wt blocks + one cnt-zero block (replaces hipMemsetAsync) ----
#define NB_CVTW 576    // (768/32)*(768/32)
__global__ __launch_bounds__(256) void k_pre(const float* __restrict__ W,
                                             unsigned short* __restrict__ Wt,
                                             int* __restrict__ cnt) {
  const int blk = blockIdx.x;
  const int t = threadIdx.x;
  if (blk < NB_CVTW) {
    __shared__ float s[32][33];
    const int n0 = (blk % 24) * 32, k0 = (blk / 24) * 32;
    const int tx = t & 31, ty = t >> 5;  // 32 x 8
#pragma unroll
    for (int i = 0; i < 4; ++i)
      s[ty + i * 8][tx] = W[(size_t)(k0 + ty + i * 8) * HD + n0 + tx];
    __syncthreads();
#pragma unroll
    for (int i = 0; i < 4; ++i)
      Wt[(size_t)(n0 + ty + i * 8) * Cv + k0 + tx] = f2b(s[tx][ty + i * 8]);
  } else {
    for (int i = t; i < Nv; i += 256) cnt[i] = 0;
  }
}

// ------ GEMM (dbuf, fused x-cvt) + attn-dot epilogue + CSR side-blocks -----
// Blocks 0..479: 128x128 tile, 4 waves, double-buffered LDS (2 blocks/CU);
// stage(k+1) before compute(k), one barrier/K-step. A: f32 load + cvt +
// swizzled ds_write; B: global_load_lds from wt. Blocks 480+: CSR build.
#define NB_GEMM 480
#define NB_SCAT ((ETOT + 255) / 256)   // 645
#define STAGEG(bi, kk)                                                         \
  {                                                                            \
    _Pragma("unroll")                                                          \
    for (int i = 0; i < 4; ++i) {                                              \
      const int r = i * 32 + rs;                                               \
      GLD16(Bt + (size_t)(bn + r) * Cv + (kk) + sl * 8, &Bs[bi][t * 8 + i * 2048]); \
    }                                                                          \
    float4 av[4][2];                                                           \
    _Pragma("unroll")                                                          \
    for (int i = 0; i < 4; ++i) {                                              \
      const int grow = bm + i * 32 + rs;                                       \
      if (grow < Mv) {                                                         \
        const float* ap = Ax + (size_t)grow * Cv + (kk) + ssl * 8;             \
        av[i][0] = *(const float4*)ap;                                         \
        av[i][1] = *(const float4*)(ap + 4);                                   \
      } else {                                                                 \
        av[i][0] = make_float4(0.f, 0.f, 0.f, 0.f);                            \
        av[i][1] = av[i][0];                                                   \
      }                                                                        \
    }                                                                          \
    _Pragma("unroll")                                                          \
    for (int i = 0; i < 4; ++i) {                                              \
      const int r = i * 32 + rs;                                               \
      unsigned short o[8];                                                     \
      o[0] = f2b(av[i][0].x); o[1] = f2b(av[i][0].y);                          \
      o[2] = f2b(av[i][0].z); o[3] = f2b(av[i][0].w);                          \
      o[4] = f2b(av[i][1].x); o[5] = f2b(av[i][1].y);                          \
      o[6] = f2b(av[i][1].z); o[7] = f2b(av[i][1].w);                          \
      const int ds = ssl ^ (r & 7);                                            \
      *(uint4*)&As[bi][r * 64 + ds * 8] = *(const uint4*)o;                    \
    }                                                                          \
  }

__global__ __launch_bounds__(256) void k_gemm_sc(const float* __restrict__ Ax,
                                                 const unsigned short* __restrict__ Bt,
                                                 unsigned short* __restrict__ C,
                                                 const float* __restrict__ att_src,
                                                 const float* __restrict__ att_dst,
                                                 float* __restrict__ asrc,
                                                 float* __restrict__ adst,
                                                 const int* __restrict__ ei,
                                                 int* __restrict__ cnt,
                                                 int* __restrict__ csrp) {
  if (blockIdx.x >= NB_GEMM) {
    const int e = (blockIdx.x - NB_GEMM) * 256 + threadIdx.x;
    if (e < ETOT) {
      int dst = (e < Ev) ? ei[Ev + e] : (e - Ev);
      int src = (e < Ev) ? ei[e] : (e - Ev);
      int pos = atomicAdd(&cnt[dst], 1);
      csrp[dst * DEGMAX + pos] = src;
    }
    return;
  }
  __shared__ unsigned short As[2][128 * 64];
  __shared__ unsigned short Bs[2][128 * 64];
  const int l0 = blockIdx.x;
  const int xcd = l0 & 7, j = l0 >> 3;        // j < 60
  const int bm = (xcd + 8 * (j / 6)) * 128;   // M-block pinned to xcd (0..79)
  const int bn = (j % 6) * 128;
  const int t = threadIdx.x;
  const int w = t >> 6, l = t & 63;
  const int wr = w >> 1, wc = w & 1;          // 2 x 2 wave grid
  const int g = l >> 4, li = l & 15;
  f32x4 acc[4][4] = {};

  const int rs = t >> 3;              // staging row within 32-row issue (0..31)
  const int ssl = t & 7;              // logical k-slot (A reg-staging)
  const int sl = ssl ^ (rs & 7);      // pre-swizzled slot for B's linear GLD

  STAGEG(0, 0);
  __syncthreads();
  int cur = 0;
#pragma unroll 1
  for (int step = 0; step < Cv / 64; ++step) {
    if (step + 1 < Cv / 64) STAGEG(cur ^ 1, (step + 1) * 64);
#pragma unroll
    for (int ks = 0; ks < 2; ++ks) {
      bf16x8 a[4], b[4];
#pragma unroll
      for (int mi = 0; mi < 4; ++mi) {
        const int row = wr * 64 + mi * 16 + li;
        const int slot = (ks * 4 + g) ^ (row & 7);
        a[mi] = *(const bf16x8*)&As[cur][row * 64 + slot * 8];
      }
#pragma unroll
      for (int nj = 0; nj < 4; ++nj) {
        const int row = wc * 64 + nj * 16 + li;
        const int slot = (ks * 4 + g) ^ (row & 7);
        b[nj] = *(const bf16x8*)&Bs[cur][row * 64 + slot * 8];
      }
#pragma unroll
      for (int mi = 0; mi < 4; ++mi)
#pragma unroll
        for (int nj = 0; nj < 4; ++nj)
          acc[mi][nj] = __builtin_amdgcn_mfma_f32_16x16x32_bf16(a[mi], b[nj], acc[mi][nj], 0, 0, 0);
    }
    __syncthreads();  // drains ds_write+GLD of next buf; protects cur for reuse
    cur ^= 1;
  }
  // C/D layout: col = lane&15, row = (lane>>4)*4 + reg (m89-verified)
#pragma unroll
  for (int mi = 0; mi < 4; ++mi) {
#pragma unroll
    for (int nj = 0; nj < 4; ++nj) {
      const int col = bn + wc * 64 + nj * 16 + li;
#pragma unroll
      for (int r4 = 0; r4 < 4; ++r4) {
        const int row = bm + wr * 64 + mi * 16 + g * 4 + r4;
        C[(size_t)row * HD + col] = f2b(acc[mi][nj][r4]);
      }
    }
  }
  // fused attention-dot epilogue: head covered by this wave's 64 cols
  {
    const int head = (bn >> 6) + wc;  // 2*(j%6) + wc
    float aS[4], aD[4];
#pragma unroll
    for (int nj = 0; nj < 4; ++nj) {
      aS[nj] = att_src[head * Dv + nj * 16 + li];
      aD[nj] = att_dst[head * Dv + nj * 16 + li];
    }
#pragma unroll
    for (int mi = 0; mi < 4; ++mi) {
#pragma unroll
      for (int r4 = 0; r4 < 4; ++r4) {
        float vs = 0.f, vd = 0.f;
#pragma unroll
        for (int nj = 0; nj < 4; ++nj) {
          const float hv = acc[mi][nj][r4];
          vs = fmaf(hv, aS[nj], vs);
          vd = fmaf(hv, aD[nj], vd);
        }
        vs += __shfl_xor(vs, 1); vd += __shfl_xor(vd, 1);
        vs += __shfl_xor(vs, 2); vd += __shfl_xor(vd, 2);
        vs += __shfl_xor(vs, 4); vd += __shfl_xor(vd, 4);
        vs += __shfl_xor(vs, 8); vd += __shfl_xor(vd, 8);
        const int row = bm + wr * 64 + mi * 16 + g * 4 + r4;
        if (li == 0 && row < Mv) {
          asrc[(size_t)row * Hv + head] = vs;
          adst[(size_t)row * Hv + head] = vd;
        }
      }
    }
  }
}

// ------- fused softmax + aggregation: block per (b, n-pair) ----------------
// R15/R19 version (best measured: 50.4us). 192 threads = 2 nodes x 96 lanes,
// batch-pinned per XCD (load-bearing: R20's batch-sharing raised L2 misses
// 46% and cost +16us).
#define EDGE_FMA(c, wv)                                              \
  {                                                                  \
    acc[0] = fmaf(wv, __uint_as_float((c).x << 16), acc[0]);         \
    acc[1] = fmaf(wv, __uint_as_float((c).x & 0xFFFF0000u), acc[1]); \
    acc[2] = fmaf(wv, __uint_as_float((c).y << 16), acc[2]);         \
    acc[3] = fmaf(wv, __uint_as_float((c).y & 0xFFFF0000u), acc[3]); \
    acc[4] = fmaf(wv, __uint_as_float((c).z << 16), acc[4]);         \
    acc[5] = fmaf(wv, __uint_as_float((c).z & 0xFFFF0000u), acc[5]); \
    acc[6] = fmaf(wv, __uint_as_float((c).w << 16), acc[6]);         \
    acc[7] = fmaf(wv, __uint_as_float((c).w & 0xFFFF0000u), acc[7]); \
  }

__global__ __launch_bounds__(192) void k_agg(const unsigned short* __restrict__ h2,
                                             const int* __restrict__ cnt,
                                             const int* __restrict__ csrp,
                                             const float* __restrict__ asrc,
                                             const float* __restrict__ adst,
                                             const float* __restrict__ bias,
                                             float* __restrict__ out) {
  const int xcd = blockIdx.x & 7;
  const int idx = blockIdx.x >> 3;        // 0..624
  const int b = xcd >> 2;
  const int pair = (xcd & 3) * 625 + idx; // 0..2499
  const int n0 = pair * 2;                // block handles n0, n0+1
  const int t = threadIdx.x;
  __shared__ int s_src[2][DEGPAD];
  __shared__ float s_w[2][Hv][DEGW];
  __shared__ float s_inv[2][16];
  const int d0 = cnt[n0], d1 = cnt[n0 + 1];  // <= DEGMAX
  for (int i = t; i < 2 * DEGPAD; i += 192) {
    const int jn = i >= DEGPAD;
    const int ii = i - jn * DEGPAD;
    const int dd = jn ? d1 : d0;
    int sv = 0;
    if (ii < dd) sv = csrp[(n0 + jn) * DEGMAX + ii];
    s_src[jn][ii] = sv;  // pad with row 0 (safe to load, weight = 0)
  }
  __syncthreads();
  // Phase A: (node jn, head-quad q, slot): one f32x4 asrc load serves 4 heads
  {
    const int jn = t / 96, rq = t % 96;
    const int q = rq >> 5, slot = rq & 31;   // q = head quad (0..2)
    const int deg = jn ? d1 : d0;
    const int degp = (deg + 7) & ~7;
    const f32x4 adv4 = *(const f32x4*)&adst[((size_t)b * Nv + n0 + jn) * Hv + q * 4];
    f32x4 ps = {0.f, 0.f, 0.f, 0.f};
    for (int i = slot; i < deg; i += 32) {
      const int src = s_src[jn][i];
      const f32x4 as4 = *(const f32x4*)&asrc[((size_t)b * Nv + src) * Hv + q * 4];
#pragma unroll
      for (int jq = 0; jq < 4; ++jq) {
        float v = as4[jq] + adv4[jq];
        v = fmaxf(v, NEG * v);      // leaky_relu
        float ex = __expf(v);
        s_w[jn][q * 4 + jq][i] = ex;
        ps[jq] += ex;
      }
    }
    for (int i = deg + slot; i < degp; i += 32) {
#pragma unroll
      for (int jq = 0; jq < 4; ++jq) s_w[jn][q * 4 + jq][i] = 0.f;
    }
#pragma unroll
    for (int jq = 0; jq < 4; ++jq) {
      ps[jq] += __shfl_xor(ps[jq], 1);
      ps[jq] += __shfl_xor(ps[jq], 2);
      ps[jq] += __shfl_xor(ps[jq], 4);
      ps[jq] += __shfl_xor(ps[jq], 8);
      ps[jq] += __shfl_xor(ps[jq], 16);
    }
    if (slot == 0) {
      f32x4 inv;
#pragma unroll
      for (int jq = 0; jq < 4; ++jq) inv[jq] = 1.0f / (ps[jq] + 1e-16f);
      *(f32x4*)&s_inv[jn][q * 4] = inv;
    }
  }
  __syncthreads();
  // Phase B: node jn, lane tl owns dims [8tl, 8tl+8); no guards (0-padded w)
  const int jn = t >= 96;
  const int tl = t - jn * 96;
  const int hl = tl >> 3;  // head
  const int degp = ((jn ? d1 : d0) + 7) & ~7;
  float acc[8] = {};
  const unsigned short* hrow = h2 + (size_t)b * Nv * HD + tl * 8;
  uint4 cA[4], cB[4];
#pragma unroll
  for (int k = 0; k < 4; ++k)
    cA[k] = *(const uint4*)(hrow + (size_t)s_src[jn][k] * HD);
  for (int base = 0; base < degp; base += 8) {
#pragma unroll
    for (int k = 0; k < 4; ++k)
      cB[k] = *(const uint4*)(hrow + (size_t)s_src[jn][base + 4 + k] * HD);
    {
      const f32x4 w4 = *(const f32x4*)&s_w[jn][hl][base];
      EDGE_FMA(cA[0], w4[0]); EDGE_FMA(cA[1], w4[1]);
      EDGE_FMA(cA[2], w4[2]); EDGE_FMA(cA[3], w4[3]);
    }
#pragma unroll
    for (int k = 0; k < 4; ++k)
      cA[k] = *(const uint4*)(hrow + (size_t)s_src[jn][base + 8 + k] * HD);  // max 131 < DEGPAD
    {
      const f32x4 w4 = *(const f32x4*)&s_w[jn][hl][base + 4];
      EDGE_FMA(cB[0], w4[0]); EDGE_FMA(cB[1], w4[1]);
      EDGE_FMA(cB[2], w4[2]); EDGE_FMA(cB[3], w4[3]);
    }
  }
  const float invh = s_inv[jn][hl];
  const int od = tl * 8;
  float4 o0, o1;
  o0.x = fmaf(acc[0], invh, bias[od + 0]);
  o0.y = fmaf(acc[1], invh, bias[od + 1]);
  o0.z = fmaf(acc[2], invh, bias[od + 2]);
  o0.w = fmaf(acc[3], invh, bias[od + 3]);
  o1.x = fmaf(acc[4], invh, bias[od + 4]);
  o1.y = fmaf(acc[5], invh, bias[od + 5]);
  o1.z = fmaf(acc[6], invh, bias[od + 6]);
  o1.w = fmaf(acc[7], invh, bias[od + 7]);
  float* op = out + ((size_t)b * Nv + n0 + jn) * HD + od;
  *(float4*)op = o0;
  *(float4*)(op + 4) = o1;
}

extern "C" void kernel_launch(void* const* d_in, const int* in_sizes, int n_in,
                              void* d_out, int out_size, void* d_ws, size_t ws_size,
                              hipStream_t stream) {
  const float* x = (const float*)d_in[0];
  const float* W = (const float*)d_in[1];
  const float* att_src = (const float*)d_in[2];
  const float* att_dst = (const float*)d_in[3];
  const float* bias = (const float*)d_in[4];
  const int* ei = (const int*)d_in[5];
  float* out = (float*)d_out;

  // workspace layout
  unsigned short* h2 = (unsigned short*)d_ws;            // MPAD*768 bf16
  unsigned short* wt = h2 + (size_t)MPAD * HD;           // 768*768 bf16
  float* asrc = (float*)(wt + (size_t)HD * Cv);          // 120,000 f32
  float* adst = asrc + (size_t)Bv * Nv * Hv;             // 120,000 f32
  int* cnt = (int*)(adst + (size_t)Bv * Nv * Hv);        // Nv (count AND cursor)
  int* csrp = cnt + Nv;                                  // Nv*DEGMAX padded CSR

  k_pre<<<NB_CVTW + 1, 256, 0, stream>>>(W, wt, cnt);
  k_gemm_sc<<<NB_GEMM + NB_SCAT, 256, 0, stream>>>(x, wt, h2, att_src, att_dst,
                                                   asrc, adst, ei, cnt, csrp);
  k_agg<<<Bv * Nv / 2, 192, 0, stream>>>(h2, cnt, csrp, asrc, adst, bias, out);
}